// Round 4
// baseline (1477.098 us; speedup 1.0000x reference)
//
#include <hip/hip_runtime.h>
#include <hip/hip_bf16.h>

// Problem constants
#define B_      4
#define CIN     128
#define HW_     256      // H == W
#define L_      65536    // H*W

// ---- workspace layout (float offsets) ---- (116 KB total, same as R3 which passed)
#define BIAS_OFF  0          // TRANSPOSED rel-pos bias biasT[h][j][i], 4*64*64
#define QKVW_OFF  16384      // 96*32
#define QKVB_OFF  19456      // 96
#define PROJW_OFF 19552      // 32*32
#define PROJB_OFF 20576      // 32
#define N1G_OFF   20608
#define N1B_OFF   20640
#define N2G_OFF   20672
#define N2B_OFF   20704
#define FC1W_OFF  20736      // 128*32
#define FC1B_OFF  24832      // 128
#define FC2T_OFF  24960      // 128*32, transposed to [i][c]
#define FC2B_OFF  29056      // 32
#define PREP_N    29088
#define MODE_OFF  29088      // int: 1 = bf16 tensors, 0 = f32 tensors

// ---- dtype helpers ----
__device__ __forceinline__ float to_f(float v) { return v; }
__device__ __forceinline__ float to_f(__hip_bfloat16 v) { return __bfloat162float(v); }
__device__ __forceinline__ void st_f(float* p, size_t i, float v) { p[i] = v; }
__device__ __forceinline__ void st_f(__hip_bfloat16* p, size_t i, float v) { p[i] = __float2bfloat16(v); }
// unpack a uint holding two bf16 (lo = lower-indexed element)
__device__ __forceinline__ float blo(unsigned u) { return __uint_as_float(u << 16); }
__device__ __forceinline__ float bhi(unsigned u) { return __uint_as_float(u & 0xffff0000u); }

// ============================ K-1: dtype detect ============================
__global__ void detect_kernel(const __hip_bfloat16* __restrict__ in0, int* __restrict__ flag) {
    __shared__ int bad;
    if (threadIdx.x == 0) bad = 0;
    __syncthreads();
    int cnt = 0;
    for (int k = 0; k < 32; k++) {
        float v = __bfloat162float(in0[threadIdx.x + k * 256]);
        if (!(fabsf(v) < 1e8f)) cnt++;
    }
    if (cnt) atomicAdd(&bad, cnt);
    __syncthreads();
    if (threadIdx.x == 0) *flag = (bad > 32) ? 0 : 1;
}

// ============================ K0: weight prep ============================
template <typename T>
__device__ void prep_impl(const T* qkv_w, const T* qkv_b, const T* rpb, const T* proj_w,
                          const T* proj_b, const T* n1g, const T* n1b, const T* n2g,
                          const T* n2b, const T* fc1_w, const T* fc1_b, const T* fc2_w,
                          const T* fc2_b, float* ws, int idx) {
    if (idx < 16384) {
        // biasT[h][j][i] = rpb_table[((dy+7)*15 + (dx+7))*4 + h], dy/dx from (i,j)
        int h = idx >> 12; int rem = idx & 4095; int j = rem >> 6; int i = rem & 63;
        int dy = (i >> 3) - (j >> 3) + 7;
        int dx = (i & 7) - (j & 7) + 7;
        ws[BIAS_OFF + idx] = to_f(rpb[(dy * 15 + dx) * 4 + h]);
        return;
    }
    int t = idx - 16384;
    if (t < 3072) { ws[QKVW_OFF + t] = to_f(qkv_w[t]); return; }
    t -= 3072;
    if (t < 96)   { ws[QKVB_OFF + t] = to_f(qkv_b[t]); return; }
    t -= 96;
    if (t < 1024) { ws[PROJW_OFF + t] = to_f(proj_w[t]); return; }
    t -= 1024;
    if (t < 32)   { ws[PROJB_OFF + t] = to_f(proj_b[t]); return; }
    t -= 32;
    if (t < 128) {
        int which = t >> 5, ln = t & 31;
        const T* src = (which == 0) ? n1g : (which == 1) ? n1b : (which == 2) ? n2g : n2b;
        int off = (which == 0) ? N1G_OFF : (which == 1) ? N1B_OFF : (which == 2) ? N2G_OFF : N2B_OFF;
        ws[off + ln] = to_f(src[ln]);
        return;
    }
    t -= 128;
    if (t < 4096) { ws[FC1W_OFF + t] = to_f(fc1_w[t]); return; }
    t -= 4096;
    if (t < 128)  { ws[FC1B_OFF + t] = to_f(fc1_b[t]); return; }
    t -= 128;
    if (t < 4096) {  // fc2_w (32,128) -> fc2t[i*32+c]
        int i = t >> 5, c = t & 31;
        ws[FC2T_OFF + t] = to_f(fc2_w[c * 128 + i]);
        return;
    }
    t -= 4096;
    ws[FC2B_OFF + t] = to_f(fc2_b[t]);
}

__global__ void prep_kernel(const void* qkv_w, const void* qkv_b, const void* rpb,
                            const void* proj_w, const void* proj_b,
                            const void* n1g, const void* n1b, const void* n2g, const void* n2b,
                            const void* fc1_w, const void* fc1_b, const void* fc2_w, const void* fc2_b,
                            float* __restrict__ ws) {
    int idx = blockIdx.x * 256 + threadIdx.x;
    if (idx >= PREP_N) return;
    const int mode = *(const int*)(ws + MODE_OFF);
    if (mode) {
        prep_impl<__hip_bfloat16>((const __hip_bfloat16*)qkv_w, (const __hip_bfloat16*)qkv_b,
            (const __hip_bfloat16*)rpb, (const __hip_bfloat16*)proj_w, (const __hip_bfloat16*)proj_b,
            (const __hip_bfloat16*)n1g, (const __hip_bfloat16*)n1b, (const __hip_bfloat16*)n2g,
            (const __hip_bfloat16*)n2b, (const __hip_bfloat16*)fc1_w, (const __hip_bfloat16*)fc1_b,
            (const __hip_bfloat16*)fc2_w, (const __hip_bfloat16*)fc2_b, ws, idx);
    } else {
        prep_impl<float>((const float*)qkv_w, (const float*)qkv_b, (const float*)rpb,
            (const float*)proj_w, (const float*)proj_b, (const float*)n1g, (const float*)n1b,
            (const float*)n2g, (const float*)n2b, (const float*)fc1_w, (const float*)fc1_b,
            (const float*)fc2_w, (const float*)fc2_b, ws, idx);
    }
}

// ============================ K1: dual conv3x3 (unchanged from R3) ============================
template <typename T>
__device__ void conv_impl(const T* __restrict__ img, const T* __restrict__ evt,
                          const T* __restrict__ cw, const T* __restrict__ cb,
                          T* __restrict__ out, float* wlds) {
    const int tid = threadIdx.x;
    const int b = blockIdx.x >> 8;
    const int h = blockIdx.x & 255;
    const int w = tid;

    float accI[16], accE[16];
#pragma unroll
    for (int c = 0; c < 16; c++) {
        float bb = to_f(cb[c]);
        accI[c] = bb; accE[c] = bb;
    }

    for (int chunk = 0; chunk < 2; chunk++) {
        const int ci0 = chunk * 64;
        __syncthreads();
        for (int k = 0; k < 36; k++) {
            int flat = tid + k * 256;
            int ci_l = flat / 144;
            int rem = flat - ci_l * 144;
            int tap = rem >> 4; int co = rem & 15;
            wlds[flat] = to_f(cw[(co * CIN + ci0 + ci_l) * 9 + tap]);
        }
        __syncthreads();

        const T* ibase = img + ((size_t)(b * CIN + ci0) * HW_ + h) * HW_ + w;
        const T* ebase = evt + ((size_t)(b * CIN + ci0) * HW_ + h) * HW_ + w;

        for (int ci = 0; ci < 64; ci++) {
            const T* ip = ibase + (size_t)ci * L_;
            const T* ep = ebase + (size_t)ci * L_;
            float vi[9], ve[9];
#pragma unroll
            for (int r = 0; r < 3; r++) {
                int hh = h + r - 1;
                bool vh = ((unsigned)hh < 256u);
                int roff = (r - 1) * 256;
#pragma unroll
                for (int c2 = 0; c2 < 3; c2++) {
                    int wwp = w + c2 - 1;
                    bool ok = vh && ((unsigned)wwp < 256u);
                    int off = roff + (c2 - 1);
                    vi[r * 3 + c2] = ok ? to_f(ip[off]) : 0.0f;
                    ve[r * 3 + c2] = ok ? to_f(ep[off]) : 0.0f;
                }
            }
            const float4* wrow = (const float4*)&wlds[ci * 144];
#pragma unroll
            for (int tap = 0; tap < 9; tap++) {
                float a = vi[tap], e2 = ve[tap];
#pragma unroll
                for (int q4 = 0; q4 < 4; q4++) {
                    float4 wv = wrow[tap * 4 + q4];
                    accI[q4 * 4 + 0] += a * wv.x;  accE[q4 * 4 + 0] += e2 * wv.x;
                    accI[q4 * 4 + 1] += a * wv.y;  accE[q4 * 4 + 1] += e2 * wv.y;
                    accI[q4 * 4 + 2] += a * wv.z;  accE[q4 * 4 + 2] += e2 * wv.z;
                    accI[q4 * 4 + 3] += a * wv.w;  accE[q4 * 4 + 3] += e2 * wv.w;
                }
            }
        }
    }

    const size_t l = (size_t)(h << 8) + w;
#pragma unroll
    for (int c = 0; c < 16; c++) {
        st_f(out, (((size_t)(b * 32 + c)) << 16) + l, accI[c]);
        st_f(out, (((size_t)(b * 32 + 16 + c)) << 16) + l, accE[c]);
    }
}

__global__ __launch_bounds__(256) void conv_kernel(const void* img, const void* evt,
                                                   const void* cw, const void* cb,
                                                   void* out, const float* __restrict__ ws) {
    __shared__ float wlds[64 * 9 * 16];
    const int mode = *(const int*)(ws + MODE_OFF);
    if (mode) {
        conv_impl<__hip_bfloat16>((const __hip_bfloat16*)img, (const __hip_bfloat16*)evt,
            (const __hip_bfloat16*)cw, (const __hip_bfloat16*)cb, (__hip_bfloat16*)out, wlds);
    } else {
        conv_impl<float>((const float*)img, (const float*)evt,
            (const float*)cw, (const float*)cb, (float*)out, wlds);
    }
}

// ============================ K2a: window attention (bf16 mode) ============================
// Block = 256 threads = 4 waves = 4 windows (lane = token). Weights in LDS.
// K/V stored bf16 in LDS, 36-element rows (72 B: b64-aligned for all rows,
// write stride 18 dwords -> conflict-light; reads are all-lane broadcasts).
// Bias is pre-transposed [h][j][i] -> lane-coalesced global reads (L2-hot).
__global__ __launch_bounds__(256) void attn_kernel(const float* __restrict__ ws,
                                                   __hip_bfloat16* __restrict__ out) {
    if (*(const int*)(ws + MODE_OFF) != 1) return;
    __shared__ __align__(16) float sw[3264];              // qkvw | qkvb | ln1g | ln1b | projb
    __shared__ __align__(16) __hip_bfloat16 pw[1024];     // proj_w bf16
    __shared__ __align__(16) __hip_bfloat162 kvK[4][64 * 18];
    __shared__ __align__(16) __hip_bfloat162 kvV[4][64 * 18];

    const int tid = threadIdx.x;
    for (int k = tid; k < 3264; k += 256) {
        float v;
        if (k < 3072)      v = ws[QKVW_OFF + k];
        else if (k < 3168) v = ws[QKVB_OFF + k - 3072];
        else if (k < 3200) v = ws[N1G_OFF + k - 3168];
        else if (k < 3232) v = ws[N1B_OFF + k - 3200];
        else               v = ws[PROJB_OFF + k - 3232];
        sw[k] = v;
    }
    for (int k = tid; k < 1024; k += 256) pw[k] = __float2bfloat16(ws[PROJW_OFF + k]);
    __syncthreads();

    const int lane = tid & 63;
    const int wv = tid >> 6;
    const int wid = blockIdx.x * 4 + wv;
    const int b = wid >> 10;
    const int r = wid & 1023;
    const int wy = r >> 5, wx = r & 31;
    const size_t l = (size_t)(((((wy << 3) + (lane >> 3))) << 8) + (wx << 3) + (lane & 7));
    const size_t base = (((size_t)b * 32) << 16) + l;

    // ---- load token + LN1 (keep only y; x reloaded at the end) ----
    float y[32];
#pragma unroll
    for (int c = 0; c < 32; c++) y[c] = __bfloat162float(out[base + ((size_t)c << 16)]);
    float mu = 0.f;
#pragma unroll
    for (int d = 0; d < 32; d++) mu += y[d];
    mu *= (1.0f / 32.0f);
    float var = 0.f;
#pragma unroll
    for (int d = 0; d < 32; d++) { float dl = y[d] - mu; var += dl * dl; }
    float rstd = rsqrtf(var * (1.0f / 32.0f) + 1e-5f);
#pragma unroll
    for (int d = 0; d < 32; d++) y[d] = (y[d] - mu) * rstd * sw[3168 + d] + sw[3200 + d];

    // ---- qkv from LDS weights ----
    const float4* qw4 = (const float4*)sw;   // 96 rows of 8 float4
    const float scale = 0.35355339059327373f;
    float qv[32];
#pragma unroll
    for (int o = 0; o < 32; o++) {
        float s = sw[3072 + o];
        const float4* wr = qw4 + o * 8;
#pragma unroll
        for (int d4 = 0; d4 < 8; d4++) {
            float4 w = wr[d4];
            s += w.x * y[d4 * 4] + w.y * y[d4 * 4 + 1] + w.z * y[d4 * 4 + 2] + w.w * y[d4 * 4 + 3];
        }
        qv[o] = s * scale;
    }
    {
        float tmp[32];
#pragma unroll
        for (int o = 0; o < 32; o++) {
            float s = sw[3072 + 32 + o];
            const float4* wr = qw4 + (32 + o) * 8;
#pragma unroll
            for (int d4 = 0; d4 < 8; d4++) {
                float4 w = wr[d4];
                s += w.x * y[d4 * 4] + w.y * y[d4 * 4 + 1] + w.z * y[d4 * 4 + 2] + w.w * y[d4 * 4 + 3];
            }
            tmp[o] = s;
        }
        __hip_bfloat162* krow = &kvK[wv][lane * 18];
#pragma unroll
        for (int d2 = 0; d2 < 16; d2++) {
            __hip_bfloat162 t;
            t.x = __float2bfloat16(tmp[2 * d2]);
            t.y = __float2bfloat16(tmp[2 * d2 + 1]);
            krow[d2] = t;
        }
#pragma unroll
        for (int o = 0; o < 32; o++) {
            float s = sw[3072 + 64 + o];
            const float4* wr = qw4 + (64 + o) * 8;
#pragma unroll
            for (int d4 = 0; d4 < 8; d4++) {
                float4 w = wr[d4];
                s += w.x * y[d4 * 4] + w.y * y[d4 * 4 + 1] + w.z * y[d4 * 4 + 2] + w.w * y[d4 * 4 + 3];
            }
            tmp[o] = s;
        }
        __hip_bfloat162* vrow = &kvV[wv][lane * 18];
#pragma unroll
        for (int d2 = 0; d2 < 16; d2++) {
            __hip_bfloat162 t;
            t.x = __float2bfloat16(tmp[2 * d2]);
            t.y = __float2bfloat16(tmp[2 * d2 + 1]);
            vrow[d2] = t;
        }
    }
    __syncthreads();   // KV visible (also a compiler ordering barrier)

    // ---- online-softmax attention, all 4 heads per j-step ----
    float m4[4] = {-1e30f, -1e30f, -1e30f, -1e30f};
    float l4[4] = {0.f, 0.f, 0.f, 0.f};
    float o32[32];
#pragma unroll
    for (int e = 0; e < 32; e++) o32[e] = 0.f;
    const float* bT = ws + BIAS_OFF;
    const __hip_bfloat162* Kb = &kvK[wv][0];
    const __hip_bfloat162* Vb = &kvV[wv][0];

    for (int j = 0; j < 64; j++) {
        const uint2* kp = (const uint2*)(Kb + j * 18);
        const uint2* vp = (const uint2*)(Vb + j * 18);
        float kf[32], vf[32];
#pragma unroll
        for (int p2 = 0; p2 < 8; p2++) {
            uint2 ku = kp[p2]; uint2 vu = vp[p2];
            kf[p2 * 4 + 0] = blo(ku.x); kf[p2 * 4 + 1] = bhi(ku.x);
            kf[p2 * 4 + 2] = blo(ku.y); kf[p2 * 4 + 3] = bhi(ku.y);
            vf[p2 * 4 + 0] = blo(vu.x); vf[p2 * 4 + 1] = bhi(vu.x);
            vf[p2 * 4 + 2] = blo(vu.y); vf[p2 * 4 + 3] = bhi(vu.y);
        }
#pragma unroll
        for (int h = 0; h < 4; h++) {
            const int hb = h * 8;
            float s = bT[((h * 64 + j) << 6) + lane];
#pragma unroll
            for (int e = 0; e < 8; e++) s += qv[hb + e] * kf[hb + e];
            float mn = fmaxf(m4[h], s);
            float p  = __expf(s - mn);
            float al = __expf(m4[h] - mn);
            l4[h] = l4[h] * al + p;
#pragma unroll
            for (int e = 0; e < 8; e++) o32[hb + e] = o32[hb + e] * al + p * vf[hb + e];
            m4[h] = mn;
        }
    }
#pragma unroll
    for (int h = 0; h < 4; h++) {
        float inv = 1.0f / l4[h];
#pragma unroll
        for (int e = 0; e < 8; e++) o32[h * 8 + e] *= inv;
    }

    // ---- proj (bf16 LDS weights) + residual; reload x, store in place ----
#pragma unroll
    for (int c = 0; c < 32; c++) {
        const uint2* wr = (const uint2*)(pw + c * 32);
        float s = sw[3232 + c];
#pragma unroll
        for (int p2 = 0; p2 < 8; p2++) {
            uint2 u = wr[p2];
            s += blo(u.x) * o32[p2 * 4 + 0] + bhi(u.x) * o32[p2 * 4 + 1]
               + blo(u.y) * o32[p2 * 4 + 2] + bhi(u.y) * o32[p2 * 4 + 3];
        }
        float xc = __bfloat162float(out[base + ((size_t)c << 16)]);
        out[base + ((size_t)c << 16)] = __float2bfloat16(xc + s);
    }
}

// ============================ K2b: LN2 + MLP (bf16 mode) ============================
__global__ __launch_bounds__(256) void mlp_kernel(const float* __restrict__ ws,
                                                  __hip_bfloat16* __restrict__ out) {
    if (*(const int*)(ws + MODE_OFF) != 1) return;
    __shared__ __align__(16) __hip_bfloat16 w1[4096];   // fc1_w [i][d]
    __shared__ __align__(16) __hip_bfloat16 w2[4096];   // fc2_t [i][c]
    __shared__ __align__(16) float sb[224];             // fc1b | fc2b | n2g | n2b

    const int tid = threadIdx.x;
    for (int k = tid; k < 4096; k += 256) {
        w1[k] = __float2bfloat16(ws[FC1W_OFF + k]);
        w2[k] = __float2bfloat16(ws[FC2T_OFF + k]);
    }
    if (tid < 224) {
        float v;
        if (tid < 128)      v = ws[FC1B_OFF + tid];
        else if (tid < 160) v = ws[FC2B_OFF + tid - 128];
        else if (tid < 192) v = ws[N2G_OFF + tid - 160];
        else                v = ws[N2B_OFF + tid - 192];
        sb[tid] = v;
    }
    __syncthreads();

    const int t = blockIdx.x * 256 + tid;
    const int b = t >> 16;
    const size_t l = (size_t)(t & 65535);
    const size_t base = (((size_t)b * 32) << 16) + l;

    float xv[32];
#pragma unroll
    for (int c = 0; c < 32; c++) xv[c] = __bfloat162float(out[base + ((size_t)c << 16)]);

    // LN2
    float mu = 0.f;
#pragma unroll
    for (int d = 0; d < 32; d++) mu += xv[d];
    mu *= (1.0f / 32.0f);
    float var = 0.f;
#pragma unroll
    for (int d = 0; d < 32; d++) { float dl = xv[d] - mu; var += dl * dl; }
    float rstd = rsqrtf(var * (1.0f / 32.0f) + 1e-5f);
    float y[32];
#pragma unroll
    for (int d = 0; d < 32; d++) y[d] = (xv[d] - mu) * rstd * sb[160 + d] + sb[192 + d];

    float acc[32];
#pragma unroll
    for (int c = 0; c < 32; c++) acc[c] = sb[128 + c];

#pragma unroll 2
    for (int i = 0; i < 128; i++) {
        const uint2* r1 = (const uint2*)(w1 + i * 32);
        float s = sb[i];
#pragma unroll
        for (int p2 = 0; p2 < 8; p2++) {
            uint2 u = r1[p2];
            s += blo(u.x) * y[p2 * 4 + 0] + bhi(u.x) * y[p2 * 4 + 1]
               + blo(u.y) * y[p2 * 4 + 2] + bhi(u.y) * y[p2 * 4 + 3];
        }
        float g = 0.5f * s * (1.0f + erff(s * 0.7071067811865475f));
        const uint2* r2 = (const uint2*)(w2 + i * 32);
#pragma unroll
        for (int p2 = 0; p2 < 8; p2++) {
            uint2 u = r2[p2];
            acc[p2 * 4 + 0] += g * blo(u.x);  acc[p2 * 4 + 1] += g * bhi(u.x);
            acc[p2 * 4 + 2] += g * blo(u.y);  acc[p2 * 4 + 3] += g * bhi(u.y);
        }
    }
#pragma unroll
    for (int c = 0; c < 32; c++)
        out[base + ((size_t)c << 16)] = __float2bfloat16(xv[c] + acc[c]);
}

// ============================ K2-fallback: f32 fused block (mode 0 only) ============================
__global__ __launch_bounds__(64) void fused_f32_kernel(const float* __restrict__ ws, float* out) {
    if (*(const int*)(ws + MODE_OFF) != 0) return;
    __shared__ float k_lds[64 * 36];
    __shared__ float v_lds[64 * 36];
    const int i = threadIdx.x;
    const int wid = blockIdx.x;
    const int b = wid >> 10;
    const int r = wid & 1023;
    const int wy = r >> 5, wx = r & 31;
    const size_t l = (size_t)((((wy << 3) + (i >> 3)) << 8) + (wx << 3) + (i & 7));
    const size_t base = (((size_t)b * 32) << 16) + l;

    float xv[32];
#pragma unroll
    for (int c = 0; c < 32; c++) xv[c] = out[base + ((size_t)c << 16)];

    float mu = 0.f;
#pragma unroll
    for (int d = 0; d < 32; d++) mu += xv[d];
    mu *= (1.0f / 32.0f);
    float var = 0.f;
#pragma unroll
    for (int d = 0; d < 32; d++) { float dl = xv[d] - mu; var += dl * dl; }
    float rstd = rsqrtf(var * (1.0f / 32.0f) + 1e-5f);
    float y[32];
#pragma unroll
    for (int d = 0; d < 32; d++)
        y[d] = (xv[d] - mu) * rstd * ws[N1G_OFF + d] + ws[N1B_OFF + d];

    const float4* qw = (const float4*)(ws + QKVW_OFF);
    const float* qb = ws + QKVB_OFF;
    const float scale = 0.35355339059327373f;
    float qv[32];
#pragma unroll
    for (int o = 0; o < 32; o++) {
        float s = qb[o];
#pragma unroll
        for (int d4 = 0; d4 < 8; d4++) {
            float4 wv = qw[o * 8 + d4];
            s += wv.x * y[d4 * 4] + wv.y * y[d4 * 4 + 1] + wv.z * y[d4 * 4 + 2] + wv.w * y[d4 * 4 + 3];
        }
        qv[o] = s * scale;
    }
#pragma unroll
    for (int o = 0; o < 32; o++) {
        float s = qb[32 + o];
#pragma unroll
        for (int d4 = 0; d4 < 8; d4++) {
            float4 wv = qw[(32 + o) * 8 + d4];
            s += wv.x * y[d4 * 4] + wv.y * y[d4 * 4 + 1] + wv.z * y[d4 * 4 + 2] + wv.w * y[d4 * 4 + 3];
        }
        k_lds[i * 36 + o] = s;
    }
#pragma unroll
    for (int o = 0; o < 32; o++) {
        float s = qb[64 + o];
#pragma unroll
        for (int d4 = 0; d4 < 8; d4++) {
            float4 wv = qw[(64 + o) * 8 + d4];
            s += wv.x * y[d4 * 4] + wv.y * y[d4 * 4 + 1] + wv.z * y[d4 * 4 + 2] + wv.w * y[d4 * 4 + 3];
        }
        v_lds[i * 36 + o] = s;
    }
    __syncthreads();

    float ao[32];
    const float* bT = ws + BIAS_OFF;   // transposed [h][j][i]
#pragma unroll
    for (int hh = 0; hh < 4; hh++) {
        float m = -1e30f, lsum = 0.f;
        float o8[8];
#pragma unroll
        for (int e = 0; e < 8; e++) o8[e] = 0.f;
        const int hb = hh * 8;
        for (int j = 0; j < 64; j++) {
            const float4* kp = (const float4*)&k_lds[j * 36 + hb];
            float4 k0 = kp[0], k1 = kp[1];
            float s = qv[hb + 0] * k0.x + qv[hb + 1] * k0.y + qv[hb + 2] * k0.z + qv[hb + 3] * k0.w
                    + qv[hb + 4] * k1.x + qv[hb + 5] * k1.y + qv[hb + 6] * k1.z + qv[hb + 7] * k1.w;
            s += bT[((hh * 64 + j) << 6) + i];
            float mn = fmaxf(m, s);
            float p = __expf(s - mn);
            float alpha = __expf(m - mn);
            lsum = lsum * alpha + p;
            const float4* vp = (const float4*)&v_lds[j * 36 + hb];
            float4 v0 = vp[0], v1 = vp[1];
            o8[0] = o8[0] * alpha + p * v0.x;  o8[1] = o8[1] * alpha + p * v0.y;
            o8[2] = o8[2] * alpha + p * v0.z;  o8[3] = o8[3] * alpha + p * v0.w;
            o8[4] = o8[4] * alpha + p * v1.x;  o8[5] = o8[5] * alpha + p * v1.y;
            o8[6] = o8[6] * alpha + p * v1.z;  o8[7] = o8[7] * alpha + p * v1.w;
            m = mn;
        }
        float inv = 1.0f / lsum;
#pragma unroll
        for (int e = 0; e < 8; e++) ao[hb + e] = o8[e] * inv;
    }

    const float4* pwf = (const float4*)(ws + PROJW_OFF);
    float xres[32];
#pragma unroll
    for (int c = 0; c < 32; c++) {
        float s = ws[PROJB_OFF + c];
#pragma unroll
        for (int d4 = 0; d4 < 8; d4++) {
            float4 wv = pwf[c * 8 + d4];
            s += wv.x * ao[d4 * 4] + wv.y * ao[d4 * 4 + 1] + wv.z * ao[d4 * 4 + 2] + wv.w * ao[d4 * 4 + 3];
        }
        xres[c] = xv[c] + s;
    }

    mu = 0.f;
#pragma unroll
    for (int d = 0; d < 32; d++) mu += xres[d];
    mu *= (1.0f / 32.0f);
    var = 0.f;
#pragma unroll
    for (int d = 0; d < 32; d++) { float dl = xres[d] - mu; var += dl * dl; }
    rstd = rsqrtf(var * (1.0f / 32.0f) + 1e-5f);
    float y2[32];
#pragma unroll
    for (int d = 0; d < 32; d++)
        y2[d] = (xres[d] - mu) * rstd * ws[N2G_OFF + d] + ws[N2B_OFF + d];

    float outv[32];
#pragma unroll
    for (int c = 0; c < 32; c++) outv[c] = ws[FC2B_OFF + c];
    const float4* w1 = (const float4*)(ws + FC1W_OFF);
    const float4* w2t = (const float4*)(ws + FC2T_OFF);
    const float* b1 = ws + FC1B_OFF;
#pragma unroll 2
    for (int ii = 0; ii < 128; ii++) {
        float s = b1[ii];
#pragma unroll
        for (int d4 = 0; d4 < 8; d4++) {
            float4 wv = w1[ii * 8 + d4];
            s += wv.x * y2[d4 * 4] + wv.y * y2[d4 * 4 + 1] + wv.z * y2[d4 * 4 + 2] + wv.w * y2[d4 * 4 + 3];
        }
        float g = 0.5f * s * (1.0f + erff(s * 0.7071067811865475f));
#pragma unroll
        for (int c4 = 0; c4 < 8; c4++) {
            float4 wv = w2t[ii * 8 + c4];
            outv[c4 * 4 + 0] += g * wv.x;  outv[c4 * 4 + 1] += g * wv.y;
            outv[c4 * 4 + 2] += g * wv.z;  outv[c4 * 4 + 3] += g * wv.w;
        }
    }
#pragma unroll
    for (int c = 0; c < 32; c++)
        out[base + ((size_t)c << 16)] = xres[c] + outv[c];
}

// ============================ launch ============================
extern "C" void kernel_launch(void* const* d_in, const int* in_sizes, int n_in,
                              void* d_out, int out_size, void* d_ws, size_t ws_size,
                              hipStream_t stream) {
    float* ws = (float*)d_ws;
    int* mode_flag = (int*)(ws + MODE_OFF);

    hipLaunchKernelGGL(detect_kernel, dim3(1), dim3(256), 0, stream,
                       (const __hip_bfloat16*)d_in[0], mode_flag);
    hipLaunchKernelGGL(prep_kernel, dim3((PREP_N + 255) / 256), dim3(256), 0, stream,
                       d_in[6], d_in[7], d_in[8], d_in[9], d_in[10],
                       d_in[4], d_in[5], d_in[11], d_in[12],
                       d_in[13], d_in[14], d_in[15], d_in[16], ws);
    hipLaunchKernelGGL(conv_kernel, dim3(B_ * HW_), dim3(256), 0, stream,
                       d_in[0], d_in[1], d_in[2], d_in[3], d_out, (const float*)ws);
    hipLaunchKernelGGL(attn_kernel, dim3(1024), dim3(256), 0, stream,
                       (const float*)ws, (__hip_bfloat16*)d_out);
    hipLaunchKernelGGL(mlp_kernel, dim3(1024), dim3(256), 0, stream,
                       (const float*)ws, (__hip_bfloat16*)d_out);
    hipLaunchKernelGGL(fused_f32_kernel, dim3(4096), dim3(64), 0, stream,
                       (const float*)ws, (float*)d_out);
}